// Round 12
// baseline (65.303 us; speedup 1.0000x reference)
//
#include <hip/hip_runtime.h>
#include <hip/hip_bf16.h>

typedef short short8 __attribute__((ext_vector_type(8)));
typedef float f32x4 __attribute__((ext_vector_type(4)));

__device__ __forceinline__ unsigned short f2bf(float f) {
  union { float f; unsigned u; } v; v.f = f;
  unsigned u = v.u;
  unsigned r = (u + 0x7FFFu + ((u >> 16) & 1u)) >> 16;  // RNE
  return (unsigned short)r;
}

// ---------------------------------------------------------------------------
// Precompute W' = W H (orthonormal Haar), closed form, fragment-packed bf16.
//   W'[e,k] = W[e,0]*2^-4 + sum_{l=1..8} (+/-) 2^{-l/2} * W[e, 2^{8-l} + (k>>l)]
//   flat index = ((nblk*8 + kk)*64 + lane)*8 + j ; e = nblk*16+(lane&15),
//   k = kk*32 + (lane>>4)*8 + j
// ---------------------------------------------------------------------------
__global__ void haar_pack(const float* __restrict__ W, unsigned short* __restrict__ Wp) {
  const int e = blockIdx.x;       // 256
  const int k = threadIdx.x;      // 256
  const float* row = W + e * 256;
  const float wgt[9] = {0.f,
    0.70710678118654752f, 0.5f, 0.35355339059327376f, 0.25f,
    0.17677669529663688f, 0.125f, 0.08838834764831844f, 0.0625f};
  float acc = row[0] * 0.0625f;
#pragma unroll
  for (int l = 1; l <= 8; ++l) {
    float g = wgt[l];
    float s = ((k >> (l - 1)) & 1) ? -g : g;
    acc += row[(1 << (8 - l)) + (k >> l)] * s;
  }
  const int nblk = e >> 4, lr = e & 15;
  const int kk = k >> 5, win = k & 31, lhi = win >> 3, j = win & 7;
  const int lane = lhi * 16 + lr;
  Wp[(((nblk * 8 + kk) * 64 + lane) << 3) + j] = f2bf(acc);
}

// ---------------------------------------------------------------------------
// R12 = R11 with NONTEMPORAL output stores (single-variable change).
// Rationale: working set x(128MB) + out(131MB) > 256MB L3; the out stream
// evicts half of x each replay -> 66MB steady HBM re-fetch competing with
// the write stream. NT (MALL-bypass) stores keep x fully L3-resident.
// Everything else identical to R11:
// - global_load_lds DMA staging (16B/lane), fp32 3-slot LDS ring, bf16
//   convert on the read side, source-side XOR swizzle (bank-conflict 0).
// - Counted vmcnt (12 steady / 8 edges) + raw s_barrier; stores never
//   drained in-loop.
// - 8 waves (2wm x 4wn), wave tile 16m x 64e; NT=16 tiles of 32 rows;
//   grid 256; mfma(W'frag, xfrag) transposed-D epilogue, dwordx4 stores.
// ---------------------------------------------------------------------------
#define NT 16

#define FSWZ(ROW) ((((ROW) & 3) << 1) | (((ROW) >> 2) & 1) | ((((ROW) >> 3) & 1) << 3))

__device__ __forceinline__ void gload16(const float* src, void* lds_dst) {
  __builtin_amdgcn_global_load_lds(
      (const __attribute__((address_space(1))) void*)src,
      (__attribute__((address_space(3))) void*)lds_dst, 16, 0, 0);
}

#define WAIT_VM(N) asm volatile("s_waitcnt vmcnt(" #N ")" ::: "memory")
#define BAR() do { __builtin_amdgcn_s_barrier(); \
                   __builtin_amdgcn_sched_barrier(0); } while (0)

__global__ __launch_bounds__(512, 1) void wemb_gemm(
    const float* __restrict__ x, const unsigned short* __restrict__ Wp,
    const float* __restrict__ bias, float* __restrict__ out) {
  __shared__ char lds[3 * 32768];
  const int tid = threadIdx.x;
  const int w = tid >> 6, lane = tid & 63;
  const int wm = w >> 2, wn = w & 3;      // 2 x 4 wave grid
  const int lr = lane & 15, lhi = lane >> 4;
  const long blockRow = (long)blockIdx.x * (32 * NT);

  // ---- W' fragments (A-operand); source proven perf-neutral R4/R6/R7 ----
  short8 Bf[8][4];   // [kk][n]
#pragma unroll
  for (int kk = 0; kk < 8; ++kk)
#pragma unroll
    for (int n = 0; n < 4; ++n)
      Bf[kk][n] = *(const short8*)(Wp + ((((wn * 4 + n) * 8 + kk) * 64 + lane) << 3));

  f32x4 bias4[4];    // e = wn*64 + n*16 + lhi*4 + r
#pragma unroll
  for (int n = 0; n < 4; ++n)
    bias4[n] = *(const f32x4*)(bias + wn * 64 + n * 16 + lhi * 4);

  // ---- staging: wave w stages rows w*4..w*4+3 of each tile (1KB/row DMA),
  //      source address lane-swizzled so linear LDS holds swizzled layout ----
#define STAGE(T)                                                              \
  {                                                                           \
    const float* xs = x + (blockRow + (long)(T) * 32) * 256;                  \
    char* slot = lds + ((T) % 3) * 32768;                                     \
    _Pragma("unroll")                                                         \
    for (int r = 0; r < 4; ++r) {                                             \
      const int row = w * 4 + r;                                              \
      const int fr = FSWZ(row);                                               \
      gload16(xs + row * 256 + ((lane ^ fr) << 2),                            \
              slot + row * 1024 + lane * 16);                                 \
    }                                                                         \
  }

  // ---- body: compute tile T from ring, stage T+2, store T (nontemporal) ----
#define BODY(T)                                                               \
  {                                                                           \
    if ((T) + 2 < NT) STAGE((T) + 2);                                         \
    __builtin_amdgcn_sched_barrier(0);                                        \
    const char* slot = lds + ((T) % 3) * 32768;                               \
    const int arow = wm * 16 + lr;                                            \
    const int fr = FSWZ(arow);                                                \
    f32x4 acc[4];                                                             \
    _Pragma("unroll")                                                         \
    for (int n = 0; n < 4; ++n) acc[n] = bias4[n];                            \
    _Pragma("unroll")                                                         \
    for (int kk = 0; kk < 8; ++kk) {                                          \
      const int u0 = kk * 8 + lhi * 2;                                        \
      f32x4 lo = *(const f32x4*)(slot + arow * 1024 + ((u0 ^ fr) << 4));      \
      f32x4 hi = *(const f32x4*)(slot + arow * 1024 + (((u0 + 1) ^ fr) << 4));\
      union { short8 s; unsigned short h[8]; } u_;                            \
      u_.h[0] = __bfloat16_as_ushort(__float2bfloat16(lo.x));                 \
      u_.h[1] = __bfloat16_as_ushort(__float2bfloat16(lo.y));                 \
      u_.h[2] = __bfloat16_as_ushort(__float2bfloat16(lo.z));                 \
      u_.h[3] = __bfloat16_as_ushort(__float2bfloat16(lo.w));                 \
      u_.h[4] = __bfloat16_as_ushort(__float2bfloat16(hi.x));                 \
      u_.h[5] = __bfloat16_as_ushort(__float2bfloat16(hi.y));                 \
      u_.h[6] = __bfloat16_as_ushort(__float2bfloat16(hi.z));                 \
      u_.h[7] = __bfloat16_as_ushort(__float2bfloat16(hi.w));                 \
      _Pragma("unroll")                                                       \
      for (int n = 0; n < 4; ++n)                                             \
        acc[n] = __builtin_amdgcn_mfma_f32_16x16x32_bf16(Bf[kk][n], u_.s,     \
                                                         acc[n], 0, 0, 0);    \
    }                                                                         \
    float* orow = out + (blockRow + (T) * 32 + wm * 16 + lr) * 256            \
                      + wn * 64 + lhi * 4;                                    \
    _Pragma("unroll")                                                         \
    for (int n = 0; n < 4; ++n)                                               \
      __builtin_nontemporal_store(acc[n], (f32x4*)(orow + n * 16));           \
  }

  // ---- prologue: stage tiles 0,1; wait for 0 ----
  STAGE(0);
  __builtin_amdgcn_sched_barrier(0);
  STAGE(1);
  __builtin_amdgcn_sched_barrier(0);
  WAIT_VM(4);          // stage(0) done (stage(1)'s 4 ops may be in flight)
  BAR();

  // Steady-state FIFO between stage(t) [body t-2] and wait(t):
  //   stores(t-2):4 + stage(t+1):4 + stores(t-1):4 = 12  -> vmcnt(12)
  // Edges: wait(1): stage(2):4+stores(0):4=8; wait(15): stores(13):4+stores(14):4=8.
#pragma unroll 1
  for (int tp = 0; tp < NT / 2; ++tp) {
    const int t0 = tp * 2;
    BODY(t0);
    if (tp == 0 || tp == NT / 2 - 1) { WAIT_VM(8); } else { WAIT_VM(12); }
    BAR();
    BODY(t0 + 1);
    if (tp < NT / 2 - 1) { WAIT_VM(12); BAR(); }
  }
#undef BODY
#undef STAGE
}

extern "C" void kernel_launch(void* const* d_in, const int* in_sizes, int n_in,
                              void* d_out, int out_size, void* d_ws, size_t ws_size,
                              hipStream_t stream) {
  const float* x = (const float*)d_in[0];     // (16, 8192, 256) fp32
  const float* W = (const float*)d_in[1];     // (256, 256) fp32
  const float* b = (const float*)d_in[2];     // (256,) fp32
  float* out = (float*)d_out;                 // (16, 8192, 256) fp32
  unsigned short* Wp = (unsigned short*)d_ws; // 256*256 bf16 = 128 KB

  haar_pack<<<256, 256, 0, stream>>>(W, Wp);

  const int grid = (out_size / 256) / (32 * NT);  // 131072 / 512 = 256
  wemb_gemm<<<grid, 512, 0, stream>>>(x, Wp, b, out);
}

// Round 13
// 57.589 us; speedup vs baseline: 1.1340x; 1.1340x over previous
//
#include <hip/hip_runtime.h>
#include <hip/hip_bf16.h>

typedef short short8 __attribute__((ext_vector_type(8)));
typedef float f32x4 __attribute__((ext_vector_type(4)));

__device__ __forceinline__ unsigned short f2bf(float f) {
  union { float f; unsigned u; } v; v.f = f;
  unsigned u = v.u;
  unsigned r = (u + 0x7FFFu + ((u >> 16) & 1u)) >> 16;  // RNE
  return (unsigned short)r;
}

// ---------------------------------------------------------------------------
// Precompute W' = W H (orthonormal Haar), closed form, fragment-packed bf16.
//   W'[e,k] = W[e,0]*2^-4 + sum_{l=1..8} (+/-) 2^{-l/2} * W[e, 2^{8-l} + (k>>l)]
//   sign = -1 if bit (l-1) of k else +1.  No barriers, no LDS.
//   flat index = ((nblk*8 + kk)*64 + lane)*8 + j ; e = nblk*16+(lane&15),
//   k = kk*32 + (lane>>4)*8 + j
// ---------------------------------------------------------------------------
__global__ void haar_pack(const float* __restrict__ W, unsigned short* __restrict__ Wp) {
  const int e = blockIdx.x;       // 256
  const int k = threadIdx.x;      // 256
  const float* row = W + e * 256;
  const float wgt[9] = {0.f,
    0.70710678118654752f, 0.5f, 0.35355339059327376f, 0.25f,
    0.17677669529663688f, 0.125f, 0.08838834764831844f, 0.0625f};
  float acc = row[0] * 0.0625f;   // cA_8 tap, weight 2^-4
#pragma unroll
  for (int l = 1; l <= 8; ++l) {
    float g = wgt[l];
    float s = ((k >> (l - 1)) & 1) ? -g : g;
    acc += row[(1 << (8 - l)) + (k >> l)] * s;
  }
  const int nblk = e >> 4, lr = e & 15;
  const int kk = k >> 5, win = k & 31, lhi = win >> 3, j = win & 7;
  const int lane = lhi * 16 + lr;
  Wp[(((nblk * 8 + kk) * 64 + lane) << 3) + j] = f2bf(acc);
}

// ---------------------------------------------------------------------------
// GEMM: out[m,e] = sum_k x[m,k] W'[e,k] + b[e] — R6 structure verbatim
// (measured best of 13 variants: 57.3 us wall). Persistent blocks, grid 256
// (1/CU), 8 waves (2 wm x 4 wn), wave tile 16x64; NTILES=16 tiles of 32 rows;
// A staged via reg->cvt->ds_write, double-buffered LDS (2x16KB), lgkm-only
// barriers (stores never drained in-loop), depth-1 reg prefetch.
// A tile XOR-swizzled: byte ^= (row&7)<<4.
// ---------------------------------------------------------------------------
#define NTILES 16
#define BM 32

__global__ __launch_bounds__(512, 2) void wemb_gemm(
    const float* __restrict__ x, const unsigned short* __restrict__ Wp,
    const float* __restrict__ bias, float* __restrict__ out) {
  __shared__ char al[2][16384];
  const int tid = threadIdx.x;
  const int w = tid >> 6, lane = tid & 63;
  const int wm = w >> 2, wn = w & 3;      // 2 x 4 wave grid
  const int lr = lane & 15, lhi = lane >> 4;

  // B fragments (allocator re-loads from L2 per iter; proven cost-neutral
  // vs LDS-resident and vs spilled-resident across R4/R6/R7)
  short8 Bf[8][4];   // [kk][n]
#pragma unroll
  for (int kk = 0; kk < 8; ++kk)
#pragma unroll
    for (int n = 0; n < 4; ++n)
      Bf[kk][n] = *(const short8*)(Wp + ((((wn * 4 + n) * 8 + kk) * 64 + lane) << 3));
#pragma unroll
  for (int kk = 0; kk < 8; ++kk)
#pragma unroll
    for (int n = 0; n < 4; ++n)
      asm volatile("" : "+v"(Bf[kk][n]));

  float bv[4];
#pragma unroll
  for (int n = 0; n < 4; ++n) bv[n] = bias[wn * 64 + n * 16 + lr];

  const long tile0 = (long)blockIdx.x * NTILES;

  // ---- prologue: stage tile 0 into al[0] ----
  {
    const float4* src = (const float4*)(x + tile0 * (BM * 256));
#pragma unroll
    for (int i = 0; i < 4; ++i) {
      int f = i * 512 + tid;
      float4 v = src[f];
      int row = f >> 6, colb = (f & 63) * 8;
      ushort4 p;
      p.x = __bfloat16_as_ushort(__float2bfloat16(v.x));
      p.y = __bfloat16_as_ushort(__float2bfloat16(v.y));
      p.z = __bfloat16_as_ushort(__float2bfloat16(v.z));
      p.w = __bfloat16_as_ushort(__float2bfloat16(v.w));
      *(ushort4*)(al[0] + row * 512 + (colb ^ ((row & 7) << 4))) = p;
    }
  }
  __syncthreads();

#pragma unroll 1
  for (int it = 0; it < NTILES; ++it) {
    const long tt = tile0 + it;
    char* cur = al[it & 1];
    char* nxt = al[(it & 1) ^ 1];

    // ---- issue prefetch of next tile (latency hides under compute+stores) ----
    float4 pf[4];
    if (it < NTILES - 1) {
      const float4* src = (const float4*)(x + (tt + 1) * (BM * 256));
#pragma unroll
      for (int i = 0; i < 4; ++i) pf[i] = src[i * 512 + tid];
    }

    // ---- compute: A from LDS, B from registers/L2 ----
    f32x4 acc[4];
#pragma unroll
    for (int n = 0; n < 4; ++n) acc[n] = (f32x4){0.f, 0.f, 0.f, 0.f};
#pragma unroll
    for (int kk = 0; kk < 8; ++kk) {
      const int arow = wm * 16 + lr;
      const int colb = (kk * 32 + lhi * 8) * 2;
      short8 a = *(const short8*)(cur + arow * 512 + (colb ^ ((arow & 7) << 4)));
#pragma unroll
      for (int n = 0; n < 4; ++n)
        acc[n] = __builtin_amdgcn_mfma_f32_16x16x32_bf16(a, Bf[kk][n], acc[n], 0, 0, 0);
    }

    // ---- store this tile (plain stores; spreads writes over time) ----
    {
      float* orow = out + (tt * BM + wm * 16 + lhi * 4) * 256;
#pragma unroll
      for (int n = 0; n < 4; ++n) {
        const int e = wn * 64 + n * 16 + lr;
#pragma unroll
        for (int r = 0; r < 4; ++r) orow[r * 256 + e] = acc[n][r] + bv[n];
      }
    }

    // ---- write next tile into the other buffer; single barrier ----
    if (it < NTILES - 1) {
#pragma unroll
      for (int i = 0; i < 4; ++i) {
        int f = i * 512 + tid;
        int row = f >> 6, colb = (f & 63) * 8;
        ushort4 p;
        p.x = __bfloat16_as_ushort(__float2bfloat16(pf[i].x));
        p.y = __bfloat16_as_ushort(__float2bfloat16(pf[i].y));
        p.z = __bfloat16_as_ushort(__float2bfloat16(pf[i].z));
        p.w = __bfloat16_as_ushort(__float2bfloat16(pf[i].w));
        *(ushort4*)(nxt + row * 512 + (colb ^ ((row & 7) << 4))) = p;
      }
    }
    __syncthreads();
  }
}

extern "C" void kernel_launch(void* const* d_in, const int* in_sizes, int n_in,
                              void* d_out, int out_size, void* d_ws, size_t ws_size,
                              hipStream_t stream) {
  const float* x = (const float*)d_in[0];     // (16, 8192, 256) fp32
  const float* W = (const float*)d_in[1];     // (256, 256) fp32
  const float* b = (const float*)d_in[2];     // (256,) fp32
  float* out = (float*)d_out;                 // (16, 8192, 256) fp32
  unsigned short* Wp = (unsigned short*)d_ws; // 256*256 bf16 = 128 KB

  haar_pack<<<256, 256, 0, stream>>>(W, Wp);

  const int grid = (out_size / 256) / (BM * NTILES);  // 131072 / 512 = 256
  wemb_gemm<<<grid, 512, 0, stream>>>(x, Wp, b, out);
}